// Round 2
// baseline (3002.391 us; speedup 1.0000x reference)
//
#include <hip/hip_runtime.h>

#define N_NODES 100000
#define N_EDGES 3200000
#define HD      32
#define NLAYERS 4
#define NGRAPHS 1000
#define BN_EPS  1e-5f
#define BSHIFT  9                         // 512-node buckets
#define NBUCK   ((N_NODES + 511) >> 9)    // 196

// ---------------- encoder: h = x*W_enc + b_enc  (+ zero-init of ws buffers) ----
__global__ __launch_bounds__(256) void k_encoder(
    const float* __restrict__ x, const float* __restrict__ W_enc,
    const float* __restrict__ b_enc, float* __restrict__ h,
    float* __restrict__ stats, float* __restrict__ pooled, int* __restrict__ bcnt)
{
    int gid = blockIdx.x * 256 + threadIdx.x;
    if (gid < NLAYERS * 64)   stats[gid]  = 0.f;   // per-layer sum/sumsq buffers
    if (gid < NGRAPHS * HD)   pooled[gid] = 0.f;
    if (gid < 256)            bcnt[gid]   = 0;
    if (gid < N_NODES * HD) {
        int i = gid >> 5, c = gid & 31;
        h[gid] = x[i] * W_enc[c] + b_enc[c];
    }
}

// ---------------- bucketed CSR build ------------------------------------------
// pass 0: coarse histogram over NBUCK buckets (LDS-aggregated)
__global__ __launch_bounds__(256) void k_bhist(const int* __restrict__ ei,
                                               int* __restrict__ bcnt)
{
    __shared__ int hist[256];
    hist[threadIdx.x] = 0;
    __syncthreads();
    int e0 = blockIdx.x * (256 * 16) + threadIdx.x;
    #pragma unroll 4
    for (int k = 0; k < 16; ++k) {
        int e = e0 + k * 256;
        if (e < N_EDGES) atomicAdd(&hist[ei[N_EDGES + e] >> BSHIFT], 1);
    }
    __syncthreads();
    int v = hist[threadIdx.x];
    if (v) atomicAdd(&bcnt[threadIdx.x], v);
}

// pass 0b: tiny scan of bucket counts -> bucket offsets & cursors
__global__ void k_bscan(const int* __restrict__ bcnt, int* __restrict__ boff,
                        int* __restrict__ bcur, int* __restrict__ off)
{
    if (threadIdx.x == 0) {
        int acc = 0;
        for (int i = 0; i < NBUCK; ++i) { boff[i] = acc; bcur[i] = acc; acc += bcnt[i]; }
        boff[NBUCK] = acc;            // == E
        off[N_NODES] = acc;           // CSR tail
    }
}

// pass 1: scatter packed edges into contiguous bucket regions (196 hot cursors)
__global__ __launch_bounds__(256) void k_bscatter(const int* __restrict__ ei,
                                                  int* __restrict__ bcur,
                                                  unsigned int* __restrict__ ebuf)
{
    int e = blockIdx.x * 256 + threadIdx.x;
    if (e < N_EDGES) {
        int src = ei[e], dst = ei[N_EDGES + e];
        int b = dst >> BSHIFT;
        int pos = atomicAdd(&bcur[b], 1);
        ebuf[pos] = ((unsigned)src << BSHIFT) | (unsigned)(dst & 511);
    }
}

// pass 2: per-bucket local sort -> final CSR + off[] (one block per bucket)
__global__ __launch_bounds__(512) void k_bfinal(const unsigned int* __restrict__ ebuf,
                                                const int* __restrict__ boff,
                                                int* __restrict__ off,
                                                int* __restrict__ csr)
{
    __shared__ int cnt[512], scanbuf[2][512], cur[512];
    int tid = threadIdx.x, b = blockIdx.x;
    int base = boff[b], nE = boff[b + 1] - base;
    cnt[tid] = 0;
    __syncthreads();
    for (int e = tid; e < nE; e += 512)
        atomicAdd(&cnt[ebuf[base + e] & 511], 1);
    __syncthreads();
    // inclusive Hillis-Steele scan over 512 (ping-pong buffers)
    int pp = 0;
    scanbuf[0][tid] = cnt[tid];
    __syncthreads();
    for (int st = 1; st < 512; st <<= 1) {
        int v = scanbuf[pp][tid];
        if (tid >= st) v += scanbuf[pp][tid - st];
        scanbuf[pp ^ 1][tid] = v;
        pp ^= 1;
        __syncthreads();
    }
    int excl = scanbuf[pp][tid] - cnt[tid];
    cur[tid] = excl;
    int gnode = (b << BSHIFT) + tid;
    if (gnode < N_NODES) off[gnode] = base + excl;
    __syncthreads();
    for (int e = tid; e < nE; e += 512) {
        unsigned int p = ebuf[base + e];
        int pos = atomicAdd(&cur[p & 511], 1);
        csr[base + pos] = (int)(p >> BSHIFT);
    }
}

// ---------------- fused layer: CSR pull + (1+eps)h + MLP, stats accumulation ---
__global__ __launch_bounds__(256) void k_layer(
    const float* __restrict__ h, const int* __restrict__ off,
    const int* __restrict__ csr, const float* __restrict__ epsArr,
    const float* __restrict__ W1, const float* __restrict__ b1,
    const float* __restrict__ W2, const float* __restrict__ b2,
    float* __restrict__ z2out, float* __restrict__ stats, int layer)
{
    __shared__ float W1s[1024], W2s[1024], b1s[32], b2s[32];
    __shared__ float z1s[256], ts[256], red[512];
    int tid = threadIdx.x;
    const float* W1l = W1 + layer * 1024;
    const float* W2l = W2 + layer * 1024;
    for (int k = tid; k < 1024; k += 256) { W1s[k] = W1l[k]; W2s[k] = W2l[k]; }
    if (tid < 32) { b1s[tid] = b1[layer * 32 + tid]; b2s[tid] = b2[layer * 32 + tid]; }
    float onePlusEps = 1.0f + epsArr[layer];
    __syncthreads();

    int slot = tid >> 5, c = tid & 31, sbase = slot * 32;
    const int NG = (N_NODES + 7) / 8;   // 12500 groups of 8 nodes
    float lsum = 0.f, lsq = 0.f;

    for (int g = blockIdx.x; g < NG; g += gridDim.x) {
        int node = g * 8 + slot;
        float z1 = 0.f;
        if (node < N_NODES) {
            int j = off[node], jend = off[node + 1];
            float acc = 0.f;
            int sNext = (j < jend) ? csr[j] : 0;     // prefetch index
            while (j < jend) {
                int s = sNext;
                ++j;
                sNext = (j < jend) ? csr[j] : 0;
                acc += h[s * HD + c];                // 128B coalesced row gather
            }
            z1 = onePlusEps * h[node * HD + c] + acc;
        }
        z1s[tid] = z1;
        __syncthreads();

        float t = b1s[c];
        #pragma unroll
        for (int k = 0; k < 32; ++k) t = fmaf(z1s[sbase + k], W1s[k * 32 + c], t);
        t = fmaxf(t, 0.f);
        ts[tid] = t;
        __syncthreads();

        float z2 = b2s[c];
        #pragma unroll
        for (int k = 0; k < 32; ++k) z2 = fmaf(ts[sbase + k], W2s[k * 32 + c], z2);

        if (node < N_NODES) {
            z2out[node * HD + c] = z2;
            lsum += z2; lsq += z2 * z2;
        }
        __syncthreads();                             // before z1s/ts reuse
    }

    red[tid] = lsum; red[256 + tid] = lsq;
    __syncthreads();
    if (tid < 64) {
        int cc = tid & 31;
        int rb = (tid < 32) ? 0 : 256;
        float s = 0.f;
        #pragma unroll
        for (int nl = 0; nl < 8; ++nl) s += red[rb + nl * 32 + cc];
        atomicAdd(&stats[layer * 64 + tid], s);      // [0..31]=sum, [32..63]=sumsq
    }
}

// ---------------- BatchNorm (batch stats) + ReLU -> h --------------------------
__global__ __launch_bounds__(256) void k_bnapply(
    const float* __restrict__ z2, const float* __restrict__ stats,
    const float* __restrict__ gamma, const float* __restrict__ beta,
    float* __restrict__ h, int layer)
{
    int gid = blockIdx.x * 256 + threadIdx.x;
    if (gid >= N_NODES * HD) return;
    int c = gid & 31;
    const float invN = 1.0f / (float)N_NODES;
    float mu  = stats[layer * 64 + c] * invN;
    float var = stats[layer * 64 + 32 + c] * invN - mu * mu;
    float scale = gamma[layer * 32 + c] * rsqrtf(var + BN_EPS);
    float shift = beta[layer * 32 + c] - mu * scale;
    h[gid] = fmaxf(fmaf(z2[gid], scale, shift), 0.f);
}

// ---------------- global_add_pool (batch is sorted -> run-length reduce) -------
__global__ __launch_bounds__(256) void k_pool(const float* __restrict__ h,
                                              const int* __restrict__ batch,
                                              float* __restrict__ pooled)
{
    int c = threadIdx.x & 31, slot = threadIdx.x >> 5;
    int start = blockIdx.x * 256 + slot * 32;        // 32 consecutive nodes per slot
    if (start >= N_NODES) return;
    int end = min(start + 32, N_NODES);
    int cur = batch[start]; float acc = 0.f;
    for (int i = start; i < end; ++i) {
        int g = batch[i];
        if (g != cur) { atomicAdd(&pooled[cur * HD + c], acc); acc = 0.f; cur = g; }
        acc += h[i * HD + c];
    }
    atomicAdd(&pooled[cur * HD + c], acc);
}

// ---------------- classifier ---------------------------------------------------
__global__ __launch_bounds__(256) void k_cls(const float* __restrict__ pooled,
                                             const float* __restrict__ Wc,
                                             const float* __restrict__ bc,
                                             float* __restrict__ out)
{
    int gid = blockIdx.x * 256 + threadIdx.x;
    if (gid >= NGRAPHS * 2) return;
    int g = gid >> 1, c = gid & 1;
    float s = bc[c];
    #pragma unroll
    for (int k = 0; k < 32; ++k) s = fmaf(pooled[g * 32 + k], Wc[k * 2 + c], s);
    out[gid] = s;
}

extern "C" void kernel_launch(void* const* d_in, const int* in_sizes, int n_in,
                              void* d_out, int out_size, void* d_ws, size_t ws_size,
                              hipStream_t stream)
{
    const float* x      = (const float*)d_in[0];
    const int*   ei     = (const int*)d_in[1];    // [2, E] int
    const int*   batch  = (const int*)d_in[2];    // [N] int, sorted
    const float* W_enc  = (const float*)d_in[3];
    const float* b_enc  = (const float*)d_in[4];
    const float* epsArr = (const float*)d_in[5];
    const float* W1     = (const float*)d_in[6];
    const float* b1     = (const float*)d_in[7];
    const float* W2     = (const float*)d_in[8];
    const float* b2     = (const float*)d_in[9];
    const float* gamma  = (const float*)d_in[10];
    const float* beta   = (const float*)d_in[11];
    const float* Wc     = (const float*)d_in[12];
    const float* bc     = (const float*)d_in[13];
    float* out = (float*)d_out;

    char* ws = (char*)d_ws;
    size_t o = 0;
    auto alloc = [&](size_t bytes) {
        char* p = ws + o;
        o += (bytes + 255) & ~(size_t)255;
        return p;
    };
    float* h      = (float*)alloc((size_t)N_NODES * HD * 4);   // 12.8 MB
    float* z2     = (float*)alloc((size_t)N_NODES * HD * 4);   // 12.8 MB
    int*   csr    = (int*)  alloc((size_t)N_EDGES * 4);        // 12.8 MB
    int*   offA   = (int*)  alloc((size_t)(N_NODES + 1) * 4);
    int*   bcnt   = (int*)  alloc(1024);
    int*   boff   = (int*)  alloc(1024);
    int*   bcur   = (int*)  alloc(1024);
    float* stats  = (float*)alloc(NLAYERS * 64 * 4);
    float* pooled = (float*)alloc((size_t)NGRAPHS * HD * 4);
    // ebuf (packed bucketed edges) aliases z2: z2 is first written by k_layer,
    // which runs only after the CSR build is complete.
    unsigned int* ebuf = (unsigned int*)z2;

    // encoder + zero-init (stats/pooled/bcnt)
    k_encoder<<<(N_NODES * HD + 255) / 256, 256, 0, stream>>>(x, W_enc, b_enc, h,
                                                              stats, pooled, bcnt);
    // bucketed CSR build (per call — ws is re-poisoned between launches)
    k_bhist   <<<(N_EDGES + 4095) / 4096, 256, 0, stream>>>(ei, bcnt);
    k_bscan   <<<1, 64, 0, stream>>>(bcnt, boff, bcur, offA);
    k_bscatter<<<(N_EDGES + 255) / 256, 256, 0, stream>>>(ei, bcur, ebuf);
    k_bfinal  <<<NBUCK, 512, 0, stream>>>(ebuf, boff, offA, csr);

    for (int l = 0; l < NLAYERS; ++l) {
        k_layer  <<<1280, 256, 0, stream>>>(h, offA, csr, epsArr, W1, b1, W2, b2,
                                            z2, stats, l);
        k_bnapply<<<(N_NODES * HD + 255) / 256, 256, 0, stream>>>(z2, stats, gamma,
                                                                  beta, h, l);
    }
    k_pool<<<(N_NODES + 255) / 256, 256, 0, stream>>>(h, batch, pooled);
    k_cls <<<8, 256, 0, stream>>>(pooled, Wc, bc, out);
}

// Round 3
// 748.313 us; speedup vs baseline: 4.0122x; 4.0122x over previous
//
#include <hip/hip_runtime.h>

#define N_NODES 100000
#define N_EDGES 3200000
#define HD      32
#define NLAYERS 4
#define NGRAPHS 1000
#define BN_EPS  1e-5f
#define BSHIFT  9                         // 512-node buckets
#define NBUCK   ((N_NODES + 511) >> 9)    // 196
#define PCHUNK  8192                      // edges per partition block
#define NPB     ((N_EDGES + PCHUNK - 1) / PCHUNK)   // 391

// ---------------- encoder: h = x*W_enc + b_enc  (+ zero-init of ws buffers) ----
__global__ __launch_bounds__(256) void k_encoder(
    const float* __restrict__ x, const float* __restrict__ W_enc,
    const float* __restrict__ b_enc, float* __restrict__ h,
    float* __restrict__ stats, float* __restrict__ pooled)
{
    int gid = blockIdx.x * 256 + threadIdx.x;
    if (gid < NLAYERS * 64)   stats[gid]  = 0.f;   // per-layer sum/sumsq buffers
    if (gid < NGRAPHS * HD)   pooled[gid] = 0.f;
    if (gid < N_NODES * HD) {
        int i = gid >> 5, c = gid & 31;
        h[gid] = x[i] * W_enc[c] + b_enc[c];
    }
}

// ---------------- deterministic radix partition (no global atomics) -----------
// pass 1: per-block histogram of its edge chunk -> pcnt[bucket*NPB + block]
__global__ __launch_bounds__(256) void k_phist(const int* __restrict__ ei,
                                               int* __restrict__ pcnt)
{
    __shared__ int hist[256];
    int t = threadIdx.x, blk = blockIdx.x;
    hist[t] = 0;
    __syncthreads();
    int e0 = blk * PCHUNK, e1 = min(e0 + PCHUNK, N_EDGES);
    for (int e = e0 + t; e < e1; e += 256)
        atomicAdd(&hist[ei[N_EDGES + e] >> BSHIFT], 1);
    __syncthreads();
    pcnt[t * NPB + blk] = hist[t];
}

// pass 2: single block — bucket totals, bucket bases, per-(bucket,block) offsets
__global__ __launch_bounds__(256) void k_pscan(int* __restrict__ pcnt,
                                               int* __restrict__ boff,
                                               int* __restrict__ off)
{
    __shared__ int sc[2][256];
    int t = threadIdx.x;
    int base = t * NPB;
    int acc = 0;
    for (int b = 0; b < NPB; ++b) acc += pcnt[base + b];
    int pp = 0;
    sc[0][t] = acc;
    __syncthreads();
    for (int st = 1; st < 256; st <<= 1) {          // inclusive scan, ping-pong
        int v = sc[pp][t];
        if (t >= st) v += sc[pp][t - st];
        sc[pp ^ 1][t] = v;
        pp ^= 1;
        __syncthreads();
    }
    int excl = sc[pp][t] - acc;
    if (t < NBUCK) boff[t] = excl;
    if (t == NBUCK - 1) { boff[NBUCK] = excl + acc; off[N_NODES] = excl + acc; }
    int run = excl;                                  // per-block running offsets
    for (int b = 0; b < NPB; ++b) {
        int v = pcnt[base + b];
        pcnt[base + b] = run;
        run += v;
    }
}

// pass 3: scatter packed edges to exact positions (LDS cursors only)
__global__ __launch_bounds__(256) void k_pscatter(const int* __restrict__ ei,
                                                  const int* __restrict__ pcnt,
                                                  unsigned int* __restrict__ ebuf)
{
    __shared__ int lcur[256];
    int t = threadIdx.x, blk = blockIdx.x;
    lcur[t] = pcnt[t * NPB + blk];
    __syncthreads();
    int e0 = blk * PCHUNK, e1 = min(e0 + PCHUNK, N_EDGES);
    for (int e = e0 + t; e < e1; e += 256) {
        int src = ei[e], dst = ei[N_EDGES + e];
        int b = dst >> BSHIFT;
        int pos = atomicAdd(&lcur[b], 1);            // LDS atomic: block-local
        ebuf[pos] = ((unsigned)src << BSHIFT) | (unsigned)(dst & 511);
    }
}

// pass 4: per-bucket local sort -> final CSR + off[] (one block per bucket)
__global__ __launch_bounds__(512) void k_bfinal(const unsigned int* __restrict__ ebuf,
                                                const int* __restrict__ boff,
                                                int* __restrict__ off,
                                                int* __restrict__ csr)
{
    __shared__ int cnt[512], scanbuf[2][512], cur[512];
    int tid = threadIdx.x, b = blockIdx.x;
    int base = boff[b], nE = boff[b + 1] - base;
    cnt[tid] = 0;
    __syncthreads();
    for (int e = tid; e < nE; e += 512)
        atomicAdd(&cnt[ebuf[base + e] & 511], 1);
    __syncthreads();
    int pp = 0;
    scanbuf[0][tid] = cnt[tid];
    __syncthreads();
    for (int st = 1; st < 512; st <<= 1) {
        int v = scanbuf[pp][tid];
        if (tid >= st) v += scanbuf[pp][tid - st];
        scanbuf[pp ^ 1][tid] = v;
        pp ^= 1;
        __syncthreads();
    }
    int excl = scanbuf[pp][tid] - cnt[tid];
    cur[tid] = excl;
    int gnode = (b << BSHIFT) + tid;
    if (gnode < N_NODES) off[gnode] = base + excl;
    __syncthreads();
    for (int e = tid; e < nE; e += 512) {
        unsigned int p = ebuf[base + e];
        int pos = atomicAdd(&cur[p & 511], 1);
        csr[base + pos] = (int)(p >> BSHIFT);
    }
}

// ---------------- fused layer: CSR pull + (1+eps)h + MLP, stats accumulation ---
__global__ __launch_bounds__(256) void k_layer(
    const float* __restrict__ h, const int* __restrict__ off,
    const int* __restrict__ csr, const float* __restrict__ epsArr,
    const float* __restrict__ W1, const float* __restrict__ b1,
    const float* __restrict__ W2, const float* __restrict__ b2,
    float* __restrict__ z2out, float* __restrict__ stats, int layer)
{
    __shared__ float W1s[1024], W2s[1024], b1s[32], b2s[32];
    __shared__ float z1s[256], ts[256], red[512];
    int tid = threadIdx.x;
    const float* W1l = W1 + layer * 1024;
    const float* W2l = W2 + layer * 1024;
    for (int k = tid; k < 1024; k += 256) { W1s[k] = W1l[k]; W2s[k] = W2l[k]; }
    if (tid < 32) { b1s[tid] = b1[layer * 32 + tid]; b2s[tid] = b2[layer * 32 + tid]; }
    float onePlusEps = 1.0f + epsArr[layer];
    __syncthreads();

    int slot = tid >> 5, c = tid & 31, sbase = slot * 32;
    const int NG = (N_NODES + 7) / 8;   // 12500 groups of 8 nodes
    float lsum = 0.f, lsq = 0.f;

    for (int g = blockIdx.x; g < NG; g += gridDim.x) {
        int node = g * 8 + slot;
        float z1 = 0.f;
        if (node < N_NODES) {
            int j = off[node], jend = off[node + 1];
            float a0 = 0.f, a1 = 0.f, a2 = 0.f, a3 = 0.f;
            while (j < jend && (j & 3)) a0 += h[csr[j++] * HD + c];  // align head
            int nb = (jend - j) >> 2;
            const int4* p = (const int4*)(csr + j);
            for (int it = 0; it < nb; ++it) {        // 4 independent gathers/iter
                int4 q = p[it];
                a0 += h[q.x * HD + c];
                a1 += h[q.y * HD + c];
                a2 += h[q.z * HD + c];
                a3 += h[q.w * HD + c];
            }
            j += nb << 2;
            while (j < jend) a0 += h[csr[j++] * HD + c];             // tail
            z1 = onePlusEps * h[node * HD + c] + (a0 + a1) + (a2 + a3);
        }
        z1s[tid] = z1;
        __syncthreads();

        float t = b1s[c];
        #pragma unroll
        for (int k = 0; k < 32; ++k) t = fmaf(z1s[sbase + k], W1s[k * 32 + c], t);
        t = fmaxf(t, 0.f);
        ts[tid] = t;
        __syncthreads();

        float z2 = b2s[c];
        #pragma unroll
        for (int k = 0; k < 32; ++k) z2 = fmaf(ts[sbase + k], W2s[k * 32 + c], z2);

        if (node < N_NODES) {
            z2out[node * HD + c] = z2;
            lsum += z2; lsq += z2 * z2;
        }
        __syncthreads();                             // before z1s/ts reuse
    }

    red[tid] = lsum; red[256 + tid] = lsq;
    __syncthreads();
    if (tid < 64) {
        int cc = tid & 31;
        int rb = (tid < 32) ? 0 : 256;
        float s = 0.f;
        #pragma unroll
        for (int nl = 0; nl < 8; ++nl) s += red[rb + nl * 32 + cc];
        atomicAdd(&stats[layer * 64 + tid], s);      // [0..31]=sum, [32..63]=sumsq
    }
}

// ---------------- BatchNorm (batch stats) + ReLU -> h --------------------------
__global__ __launch_bounds__(256) void k_bnapply(
    const float* __restrict__ z2, const float* __restrict__ stats,
    const float* __restrict__ gamma, const float* __restrict__ beta,
    float* __restrict__ h, int layer)
{
    int gid = blockIdx.x * 256 + threadIdx.x;
    if (gid >= N_NODES * HD) return;
    int c = gid & 31;
    const float invN = 1.0f / (float)N_NODES;
    float mu  = stats[layer * 64 + c] * invN;
    float var = stats[layer * 64 + 32 + c] * invN - mu * mu;
    float scale = gamma[layer * 32 + c] * rsqrtf(var + BN_EPS);
    float shift = beta[layer * 32 + c] - mu * scale;
    h[gid] = fmaxf(fmaf(z2[gid], scale, shift), 0.f);
}

// ---------------- global_add_pool (batch is sorted -> run-length reduce) -------
__global__ __launch_bounds__(256) void k_pool(const float* __restrict__ h,
                                              const int* __restrict__ batch,
                                              float* __restrict__ pooled)
{
    int c = threadIdx.x & 31, slot = threadIdx.x >> 5;
    int start = blockIdx.x * 256 + slot * 32;        // 32 consecutive nodes per slot
    if (start >= N_NODES) return;
    int end = min(start + 32, N_NODES);
    int cur = batch[start]; float acc = 0.f;
    for (int i = start; i < end; ++i) {
        int g = batch[i];
        if (g != cur) { atomicAdd(&pooled[cur * HD + c], acc); acc = 0.f; cur = g; }
        acc += h[i * HD + c];
    }
    atomicAdd(&pooled[cur * HD + c], acc);
}

// ---------------- classifier ---------------------------------------------------
__global__ __launch_bounds__(256) void k_cls(const float* __restrict__ pooled,
                                             const float* __restrict__ Wc,
                                             const float* __restrict__ bc,
                                             float* __restrict__ out)
{
    int gid = blockIdx.x * 256 + threadIdx.x;
    if (gid >= NGRAPHS * 2) return;
    int g = gid >> 1, c = gid & 1;
    float s = bc[c];
    #pragma unroll
    for (int k = 0; k < 32; ++k) s = fmaf(pooled[g * 32 + k], Wc[k * 2 + c], s);
    out[gid] = s;
}

extern "C" void kernel_launch(void* const* d_in, const int* in_sizes, int n_in,
                              void* d_out, int out_size, void* d_ws, size_t ws_size,
                              hipStream_t stream)
{
    const float* x      = (const float*)d_in[0];
    const int*   ei     = (const int*)d_in[1];    // [2, E] int
    const int*   batch  = (const int*)d_in[2];    // [N] int, sorted
    const float* W_enc  = (const float*)d_in[3];
    const float* b_enc  = (const float*)d_in[4];
    const float* epsArr = (const float*)d_in[5];
    const float* W1     = (const float*)d_in[6];
    const float* b1     = (const float*)d_in[7];
    const float* W2     = (const float*)d_in[8];
    const float* b2     = (const float*)d_in[9];
    const float* gamma  = (const float*)d_in[10];
    const float* beta   = (const float*)d_in[11];
    const float* Wc     = (const float*)d_in[12];
    const float* bc     = (const float*)d_in[13];
    float* out = (float*)d_out;

    char* ws = (char*)d_ws;
    size_t o = 0;
    auto alloc = [&](size_t bytes) {
        char* p = ws + o;
        o += (bytes + 255) & ~(size_t)255;
        return p;
    };
    float* h      = (float*)alloc((size_t)N_NODES * HD * 4);   // 12.8 MB
    float* z2     = (float*)alloc((size_t)N_NODES * HD * 4);   // 12.8 MB
    int*   csr    = (int*)  alloc((size_t)N_EDGES * 4);        // 12.8 MB
    int*   offA   = (int*)  alloc((size_t)(N_NODES + 1) * 4);
    int*   pcnt   = (int*)  alloc((size_t)256 * NPB * 4);      // 0.4 MB
    int*   boff   = (int*)  alloc(1024);
    float* stats  = (float*)alloc(NLAYERS * 64 * 4);
    float* pooled = (float*)alloc((size_t)NGRAPHS * HD * 4);
    // ebuf (packed bucketed edges) aliases z2: z2 is first written by k_layer,
    // which runs only after the CSR build is complete.
    unsigned int* ebuf = (unsigned int*)z2;

    // encoder + zero-init (stats/pooled)
    k_encoder<<<(N_NODES * HD + 255) / 256, 256, 0, stream>>>(x, W_enc, b_enc, h,
                                                              stats, pooled);
    // deterministic radix partition + per-bucket CSR finalize
    k_phist   <<<NPB, 256, 0, stream>>>(ei, pcnt);
    k_pscan   <<<1, 256, 0, stream>>>(pcnt, boff, offA);
    k_pscatter<<<NPB, 256, 0, stream>>>(ei, pcnt, ebuf);
    k_bfinal  <<<NBUCK, 512, 0, stream>>>(ebuf, boff, offA, csr);

    for (int l = 0; l < NLAYERS; ++l) {
        k_layer  <<<1280, 256, 0, stream>>>(h, offA, csr, epsArr, W1, b1, W2, b2,
                                            z2, stats, l);
        k_bnapply<<<(N_NODES * HD + 255) / 256, 256, 0, stream>>>(z2, stats, gamma,
                                                                  beta, h, l);
    }
    k_pool<<<(N_NODES + 255) / 256, 256, 0, stream>>>(h, batch, pooled);
    k_cls <<<8, 256, 0, stream>>>(pooled, Wc, bc, out);
}